// Round 7
// baseline (1196.545 us; speedup 1.0000x reference)
//
#include <hip/hip_runtime.h>

#define HD 128

constexpr int N_ATOMS = 20000;
constexpr int N_EDGES = 320000;
constexpr int NLAY   = 4;
constexpr int NMOL   = 200;
constexpr float FCUT  = 5.0f;
constexpr float DELTA = FCUT / 127.0f;
constexpr float GCOEFF = -0.5f / (DELTA * DELTA);
constexpr float PI_F  = 3.14159265358979323846f;
constexpr float LN2F  = 0.6931471805599453f;

__device__ __forceinline__ float sspf(float x) {
  return fmaxf(x, 0.0f) + log1pf(expf(-fabsf(x))) - LN2F;
}
__device__ __forceinline__ float sigmf(float x) {
  return 1.0f / (1.0f + expf(-x));
}

// bf16 pack/unpack (round-to-nearest-even)
__device__ __forceinline__ unsigned bfpack(float a, float b) {
  unsigned ua = __float_as_uint(a);
  unsigned ub = __float_as_uint(b);
  ua = (ua + 0x7FFFu + ((ua >> 16) & 1u)) >> 16;
  ub = (ub + 0x7FFFu + ((ub >> 16) & 1u)) >> 16;
  return (ub << 16) | ua;
}
__device__ __forceinline__ float bflo(unsigned p) { return __uint_as_float(p << 16); }
__device__ __forceinline__ float bfhi(unsigned p) { return __uint_as_float(p & 0xFFFF0000u); }

// ------------------------------------------------------------------
// small elementwise kernels
// ------------------------------------------------------------------

__global__ __launch_bounds__(256) void geom_k(
    const float* __restrict__ pos, const int* __restrict__ row,
    const int* __restrict__ col, float* __restrict__ dist)
{
  int e = blockIdx.x * 256 + threadIdx.x;
  if (e >= N_EDGES) return;
  int r = row[e], c = col[e];
  float dx = pos[3*r+0] - pos[3*c+0];
  float dy = pos[3*r+1] - pos[3*c+1];
  float dz = pos[3*r+2] - pos[3*c+2];
  dist[e] = sqrtf(dx*dx + dy*dy + dz*dz);
}

__global__ __launch_bounds__(256) void h0_k(
    const float* __restrict__ emb, const int* __restrict__ z,
    float* __restrict__ h0)
{
  int i = blockIdx.x * 256 + threadIdx.x;
  if (i >= N_ATOMS * HD) return;
  int n = i >> 7, k = i & 127;
  h0[i] = emb[z[n] * HD + k];
}

// ------------------------------------------------------------------
// CSR build: histogram, scan, scatter
// ------------------------------------------------------------------
__global__ __launch_bounds__(256) void hist_k(
    const int* __restrict__ idx, int* __restrict__ cnt)
{
  int e = blockIdx.x * 256 + threadIdx.x;
  if (e >= N_EDGES) return;
  atomicAdd(&cnt[idx[e]], 1);
}

__global__ __launch_bounds__(256) void scan_k(
    const int* __restrict__ cnt, int* __restrict__ ptr)
{
  constexpr int CH = 79;  // 256*79 = 20224 >= 20001
  __shared__ int part[256];
  int t = threadIdx.x;
  int base = t * CH;
  int s = 0;
  for (int i = 0; i < CH; i++) {
    int idx = base + i;
    if (idx < N_ATOMS) s += cnt[idx];
  }
  part[t] = s;
  __syncthreads();
  for (int off = 1; off < 256; off <<= 1) {
    int u = (t >= off) ? part[t - off] : 0;
    __syncthreads();
    part[t] += u;
    __syncthreads();
  }
  int run = part[t] - s;
  for (int i = 0; i < CH; i++) {
    int idx = base + i;
    if (idx > N_ATOMS) break;
    ptr[idx] = run;
    if (idx < N_ATOMS) run += cnt[idx];
  }
}

// CSR by row (backward + force): also records edge -> row-slot map
__global__ __launch_bounds__(256) void scat_row_k(
    const int* __restrict__ row, const int* __restrict__ col,
    const float* __restrict__ dist, int* __restrict__ cur,
    int* __restrict__ rother, float* __restrict__ rdist,
    int* __restrict__ slotof)
{
  int e = blockIdx.x * 256 + threadIdx.x;
  if (e >= N_EDGES) return;
  int p = atomicAdd(&cur[row[e]], 1);
  rother[p] = col[e];
  rdist[p] = dist[e];
  slotof[e] = p;
}

// CSR by col (forward + force): stores row-slot of the edge
__global__ __launch_bounds__(256) void scat_col_k(
    const int* __restrict__ row, const int* __restrict__ col,
    const float* __restrict__ dist, int* __restrict__ cur,
    int* __restrict__ cother, float* __restrict__ cdist,
    const int* __restrict__ slotof, int* __restrict__ cslot)
{
  int e = blockIdx.x * 256 + threadIdx.x;
  if (e >= N_EDGES) return;
  int p = atomicAdd(&cur[col[e]], 1);
  cother[p] = row[e];
  cdist[p] = dist[e];
  cslot[p] = slotof[e];
}

// ------------------------------------------------------------------
// table build
// ------------------------------------------------------------------
__global__ __launch_bounds__(256) void nodeA_k(
    float* __restrict__ A, float* __restrict__ dA, int nnode, float hstep)
{
  int i = blockIdx.x * 256 + threadIdx.x;
  if (i >= nnode * HD) return;
  int node = i >> 7, g = i & 127;
  float d = (float)node * hstep;
  float t = d - (float)g * DELTA;
  float a = expf(GCOEFF * t * t);
  A[i] = a;
  dA[i] = a * 2.0f * GCOEFF * t;
}

__global__ __launch_bounds__(256) void nodeact_k(
    const float* __restrict__ t1, const float* __restrict__ u,
    float* __restrict__ s, float* __restrict__ sp, int total)
{
  int i = blockIdx.x * 256 + threadIdx.x;
  if (i >= total) return;
  float x = t1[i];
  s[i] = sspf(x);
  sp[i] = sigmf(x) * u[i];
}

// T[l][node][ch] = bf16 pair { P0*C (lo) , D0*C + P0*C' (hi) }
__global__ __launch_bounds__(256) void nodecomb_k(
    const float* __restrict__ P0, const float* __restrict__ D0,
    unsigned* __restrict__ T, int nnode, float hstep)
{
  int i = blockIdx.x * 256 + threadIdx.x;
  int total = NLAY * nnode * HD;
  if (i >= total) return;
  int rem = i % (nnode * HD);
  int node = rem >> 7;
  float d = (float)node * hstep;
  float C  = 0.5f * cosf(d * (PI_F / FCUT)) + 0.5f;
  float Cp = -0.5f * sinf(d * (PI_F / FCUT)) * (PI_F / FCUT);
  float p = P0[i], q = D0[i];
  T[i] = bfpack(p * C, q * C + p * Cp);
}

// ------------------------------------------------------------------
// generic fp32 GEMM: C[M,128] = epi( A[M,128] @ B(^T) + bias )
// EPI: 0: acc+bias   1: acc+bias+EP1
// OB : output bf16 (packed pairs) instead of fp32
// ------------------------------------------------------------------
template<int EPI, bool BT, bool OB>
__global__ __launch_bounds__(256) void gemm128_k(
    const float* __restrict__ A, const float* __restrict__ B,
    const float* __restrict__ bias, const float* __restrict__ EP1,
    float* __restrict__ C, int M)
{
  __shared__ float As[16][68];
  __shared__ float Bs[16][132];
  int t = threadIdx.x;
  int tx = t & 15, ty = t >> 4;
  int m0 = blockIdx.x * 64;

  float acc[4][8];
#pragma unroll
  for (int r = 0; r < 4; r++)
#pragma unroll
    for (int c = 0; c < 8; c++) acc[r][c] = 0.0f;

  for (int k0 = 0; k0 < HD; k0 += 16) {
    {
      int rrow = t >> 2;
      int kg = (t & 3) * 4;
      int gm = m0 + rrow;
      float4 av = make_float4(0.f, 0.f, 0.f, 0.f);
      if (gm < M) av = *(const float4*)(A + (size_t)gm * HD + k0 + kg);
      As[kg+0][rrow] = av.x; As[kg+1][rrow] = av.y;
      As[kg+2][rrow] = av.z; As[kg+3][rrow] = av.w;
    }
    if (!BT) {
#pragma unroll
      for (int it = 0; it < 2; it++) {
        int f4 = t + it * 256;
        int kk = f4 >> 5;
        int n4 = (f4 & 31) * 4;
        float4 bv = *(const float4*)(B + (size_t)(k0 + kk) * HD + n4);
        *(float4*)&Bs[kk][n4] = bv;
      }
    } else {
#pragma unroll
      for (int it = 0; it < 2; it++) {
        int idx = t + it * 256;
        int n = idx >> 2;
        int kg = (idx & 3) * 4;
        float4 bv = *(const float4*)(B + (size_t)n * HD + k0 + kg);
        Bs[kg+0][n] = bv.x; Bs[kg+1][n] = bv.y;
        Bs[kg+2][n] = bv.z; Bs[kg+3][n] = bv.w;
      }
    }
    __syncthreads();
#pragma unroll
    for (int kk = 0; kk < 16; kk++) {
      float a[4], b[8];
#pragma unroll
      for (int r = 0; r < 4; r++) a[r] = As[kk][ty * 4 + r];
#pragma unroll
      for (int c = 0; c < 8; c++) b[c] = Bs[kk][tx * 8 + c];
#pragma unroll
      for (int r = 0; r < 4; r++)
#pragma unroll
        for (int c = 0; c < 8; c++) acc[r][c] = fmaf(a[r], b[c], acc[r][c]);
    }
    __syncthreads();
  }

  int n0 = tx * 8;
  float bv[8];
#pragma unroll
  for (int c = 0; c < 8; c++) bv[c] = bias ? bias[n0 + c] : 0.0f;
#pragma unroll
  for (int r = 0; r < 4; r++) {
    int gm = m0 + ty * 4 + r;
    if (gm >= M) continue;
    float out[8];
#pragma unroll
    for (int c = 0; c < 8; c++) {
      float x = acc[r][c] + bv[c];
      if (EPI == 1) x += EP1[(size_t)gm * HD + n0 + c];
      out[c] = x;
    }
    if (OB) {
      uint4 pk;
      pk.x = bfpack(out[0], out[1]);
      pk.y = bfpack(out[2], out[3]);
      pk.z = bfpack(out[4], out[5]);
      pk.w = bfpack(out[6], out[7]);
      *(uint4*)((unsigned*)C + (size_t)gm * 64 + tx * 4) = pk;
    } else {
      *(float4*)(C + (size_t)gm * HD + n0)     = *(float4*)&out[0];
      *(float4*)(C + (size_t)gm * HD + n0 + 4) = *(float4*)&out[4];
    }
  }
}

// batched (over blockIdx.y = layer) plain GEMM for table build
__global__ __launch_bounds__(256) void gemm128b_k(
    const float* __restrict__ A, size_t astride,
    const float* __restrict__ B, size_t bstride,
    const float* __restrict__ bias, size_t biasstride,
    float* __restrict__ C, size_t cstride, int M)
{
  int l = blockIdx.y;
  A += (size_t)l * astride;
  B += (size_t)l * bstride;
  if (bias) bias += (size_t)l * biasstride;
  C += (size_t)l * cstride;

  __shared__ float As[16][68];
  __shared__ float Bs[16][132];
  int t = threadIdx.x;
  int tx = t & 15, ty = t >> 4;
  int m0 = blockIdx.x * 64;

  float acc[4][8];
#pragma unroll
  for (int r = 0; r < 4; r++)
#pragma unroll
    for (int c = 0; c < 8; c++) acc[r][c] = 0.0f;

  for (int k0 = 0; k0 < HD; k0 += 16) {
    {
      int rrow = t >> 2;
      int kg = (t & 3) * 4;
      int gm = m0 + rrow;
      float4 av = make_float4(0.f, 0.f, 0.f, 0.f);
      if (gm < M) av = *(const float4*)(A + (size_t)gm * HD + k0 + kg);
      As[kg+0][rrow] = av.x; As[kg+1][rrow] = av.y;
      As[kg+2][rrow] = av.z; As[kg+3][rrow] = av.w;
    }
#pragma unroll
    for (int it = 0; it < 2; it++) {
      int f4 = t + it * 256;
      int kk = f4 >> 5;
      int n4 = (f4 & 31) * 4;
      float4 bv = *(const float4*)(B + (size_t)(k0 + kk) * HD + n4);
      *(float4*)&Bs[kk][n4] = bv;
    }
    __syncthreads();
#pragma unroll
    for (int kk = 0; kk < 16; kk++) {
      float a[4], b[8];
#pragma unroll
      for (int r = 0; r < 4; r++) a[r] = As[kk][ty * 4 + r];
#pragma unroll
      for (int c = 0; c < 8; c++) b[c] = Bs[kk][tx * 8 + c];
#pragma unroll
      for (int r = 0; r < 4; r++)
#pragma unroll
        for (int c = 0; c < 8; c++) acc[r][c] = fmaf(a[r], b[c], acc[r][c]);
    }
    __syncthreads();
  }

  int n0 = tx * 8;
  float bv[8];
#pragma unroll
  for (int c = 0; c < 8; c++) bv[c] = bias ? bias[n0 + c] : 0.0f;
#pragma unroll
  for (int r = 0; r < 4; r++) {
    int gm = m0 + ty * 4 + r;
    if (gm >= M) continue;
    float out[8];
#pragma unroll
    for (int c = 0; c < 8; c++) out[c] = acc[r][c] + bv[c];
    *(float4*)(C + (size_t)gm * HD + n0)     = *(float4*)&out[0];
    *(float4*)(C + (size_t)gm * HD + n0 + 4) = *(float4*)&out[4];
  }
}

// ------------------------------------------------------------------
// fused fwd tail (3 phases):
//   V  = agg@l2 + l2b          (stored fp32)
//   h' = h + ssp(V)@bw + bb    (stored fp32)
//   hx'= h' @ l1n              (stored bf16-packed; skipped if l1n==null)
// Ss padded to 133 to kill the 8-way bank conflict on column reads.
// ------------------------------------------------------------------
__global__ __launch_bounds__(256) void ftail_k(
    const float* __restrict__ agg, const float* __restrict__ l2,
    const float* __restrict__ l2b, const float* __restrict__ bw,
    const float* __restrict__ bb, const float* __restrict__ h,
    const float* __restrict__ l1n, float* __restrict__ vbuf,
    float* __restrict__ hout, unsigned* __restrict__ hxn, int M)
{
  __shared__ float As[16][68];
  __shared__ float Bs[16][132];
  __shared__ float Ss[64][133];
  int t = threadIdx.x;
  int tx = t & 15, ty = t >> 4;
  int m0 = blockIdx.x * 64;

  float acc[4][8];
#pragma unroll
  for (int r = 0; r < 4; r++)
#pragma unroll
    for (int c = 0; c < 8; c++) acc[r][c] = 0.0f;

  // phase 1: V = agg @ l2
  for (int k0 = 0; k0 < HD; k0 += 16) {
    {
      int rrow = t >> 2;
      int kg = (t & 3) * 4;
      int gm = m0 + rrow;
      float4 av = make_float4(0.f, 0.f, 0.f, 0.f);
      if (gm < M) av = *(const float4*)(agg + (size_t)gm * HD + k0 + kg);
      As[kg+0][rrow] = av.x; As[kg+1][rrow] = av.y;
      As[kg+2][rrow] = av.z; As[kg+3][rrow] = av.w;
    }
#pragma unroll
    for (int it = 0; it < 2; it++) {
      int f4 = t + it * 256;
      int kk = f4 >> 5;
      int n4 = (f4 & 31) * 4;
      float4 bv = *(const float4*)(l2 + (size_t)(k0 + kk) * HD + n4);
      *(float4*)&Bs[kk][n4] = bv;
    }
    __syncthreads();
#pragma unroll
    for (int kk = 0; kk < 16; kk++) {
      float a[4], b[8];
#pragma unroll
      for (int r = 0; r < 4; r++) a[r] = As[kk][ty * 4 + r];
#pragma unroll
      for (int c = 0; c < 8; c++) b[c] = Bs[kk][tx * 8 + c];
#pragma unroll
      for (int r = 0; r < 4; r++)
#pragma unroll
        for (int c = 0; c < 8; c++) acc[r][c] = fmaf(a[r], b[c], acc[r][c]);
    }
    __syncthreads();
  }

  int n0 = tx * 8;
  {
    float l2bv[8];
#pragma unroll
    for (int c = 0; c < 8; c++) l2bv[c] = l2b[n0 + c];
#pragma unroll
    for (int r = 0; r < 4; r++) {
      int lr = ty * 4 + r;
      int gm = m0 + lr;
      float vv[8];
#pragma unroll
      for (int c = 0; c < 8; c++) {
        float x = acc[r][c] + l2bv[c];
        vv[c] = x;
        Ss[lr][n0 + c] = sspf(x);
      }
      if (gm < M) {
        *(float4*)(vbuf + (size_t)gm * HD + n0)     = *(float4*)&vv[0];
        *(float4*)(vbuf + (size_t)gm * HD + n0 + 4) = *(float4*)&vv[4];
      }
    }
  }
  __syncthreads();

  // phase 2: h' = h + ssp(V) @ bw + bb
#pragma unroll
  for (int r = 0; r < 4; r++)
#pragma unroll
    for (int c = 0; c < 8; c++) acc[r][c] = 0.0f;

  for (int k0 = 0; k0 < HD; k0 += 16) {
#pragma unroll
    for (int it = 0; it < 2; it++) {
      int f4 = t + it * 256;
      int kk = f4 >> 5;
      int n4 = (f4 & 31) * 4;
      float4 bv = *(const float4*)(bw + (size_t)(k0 + kk) * HD + n4);
      *(float4*)&Bs[kk][n4] = bv;
    }
    __syncthreads();
#pragma unroll
    for (int kk = 0; kk < 16; kk++) {
      float a[4], b[8];
#pragma unroll
      for (int r = 0; r < 4; r++) a[r] = Ss[ty * 4 + r][k0 + kk];
#pragma unroll
      for (int c = 0; c < 8; c++) b[c] = Bs[kk][tx * 8 + c];
#pragma unroll
      for (int r = 0; r < 4; r++)
#pragma unroll
        for (int c = 0; c < 8; c++) acc[r][c] = fmaf(a[r], b[c], acc[r][c]);
    }
    __syncthreads();
  }

  {
    float bbv[8];
#pragma unroll
    for (int c = 0; c < 8; c++) bbv[c] = bb[n0 + c];
#pragma unroll
    for (int r = 0; r < 4; r++) {
      int lr = ty * 4 + r;
      int gm = m0 + lr;
      float4 h0v = make_float4(0.f,0.f,0.f,0.f), h1v = make_float4(0.f,0.f,0.f,0.f);
      if (gm < M) {
        h0v = *(const float4*)(h + (size_t)gm * HD + n0);
        h1v = *(const float4*)(h + (size_t)gm * HD + n0 + 4);
      }
      float ov[8];
      ov[0] = acc[r][0] + bbv[0] + h0v.x;
      ov[1] = acc[r][1] + bbv[1] + h0v.y;
      ov[2] = acc[r][2] + bbv[2] + h0v.z;
      ov[3] = acc[r][3] + bbv[3] + h0v.w;
      ov[4] = acc[r][4] + bbv[4] + h1v.x;
      ov[5] = acc[r][5] + bbv[5] + h1v.y;
      ov[6] = acc[r][6] + bbv[6] + h1v.z;
      ov[7] = acc[r][7] + bbv[7] + h1v.w;
      if (gm < M) {
        *(float4*)(hout + (size_t)gm * HD + n0)     = *(float4*)&ov[0];
        *(float4*)(hout + (size_t)gm * HD + n0 + 4) = *(float4*)&ov[4];
      }
      if (l1n) {
#pragma unroll
        for (int c = 0; c < 8; c++) Ss[lr][n0 + c] = ov[c];
      }
    }
  }

  // phase 3: hx' = h' @ l1n (bf16 out), only when l1n provided
  if (l1n) {
#pragma unroll
    for (int r = 0; r < 4; r++)
#pragma unroll
      for (int c = 0; c < 8; c++) acc[r][c] = 0.0f;

    for (int k0 = 0; k0 < HD; k0 += 16) {
#pragma unroll
      for (int it = 0; it < 2; it++) {
        int f4 = t + it * 256;
        int kk = f4 >> 5;
        int n4 = (f4 & 31) * 4;
        float4 bv = *(const float4*)(l1n + (size_t)(k0 + kk) * HD + n4);
        *(float4*)&Bs[kk][n4] = bv;
      }
      __syncthreads();
#pragma unroll
      for (int kk = 0; kk < 16; kk++) {
        float a[4], b[8];
#pragma unroll
        for (int r = 0; r < 4; r++) a[r] = Ss[ty * 4 + r][k0 + kk];
#pragma unroll
        for (int c = 0; c < 8; c++) b[c] = Bs[kk][tx * 8 + c];
#pragma unroll
        for (int r = 0; r < 4; r++)
#pragma unroll
          for (int c = 0; c < 8; c++) acc[r][c] = fmaf(a[r], b[c], acc[r][c]);
      }
      __syncthreads();
    }
#pragma unroll
    for (int r = 0; r < 4; r++) {
      int gm = m0 + ty * 4 + r;
      if (gm >= M) continue;
      uint4 pk;
      pk.x = bfpack(acc[r][0], acc[r][1]);
      pk.y = bfpack(acc[r][2], acc[r][3]);
      pk.z = bfpack(acc[r][4], acc[r][5]);
      pk.w = bfpack(acc[r][6], acc[r][7]);
      *(uint4*)(hxn + (size_t)gm * 64 + tx * 4) = pk;
    }
  }
}

// ------------------------------------------------------------------
// fused bwd head: dv = (g@bw^T)*sigm(v), dagg = dv@l2^T (bf16 out)
// ------------------------------------------------------------------
__global__ __launch_bounds__(256) void bhead_k(
    const float* __restrict__ g, const float* __restrict__ bw,
    const float* __restrict__ v, const float* __restrict__ l2,
    unsigned* __restrict__ dagg, int M)
{
  __shared__ float As[16][68];
  __shared__ float Bs[16][132];
  __shared__ float Ss[64][133];
  int t = threadIdx.x;
  int tx = t & 15, ty = t >> 4;
  int m0 = blockIdx.x * 64;

  float acc[4][8];
#pragma unroll
  for (int r = 0; r < 4; r++)
#pragma unroll
    for (int c = 0; c < 8; c++) acc[r][c] = 0.0f;

  for (int k0 = 0; k0 < HD; k0 += 16) {
    {
      int rrow = t >> 2;
      int kg = (t & 3) * 4;
      int gm = m0 + rrow;
      float4 av = make_float4(0.f, 0.f, 0.f, 0.f);
      if (gm < M) av = *(const float4*)(g + (size_t)gm * HD + k0 + kg);
      As[kg+0][rrow] = av.x; As[kg+1][rrow] = av.y;
      As[kg+2][rrow] = av.z; As[kg+3][rrow] = av.w;
    }
#pragma unroll
    for (int it = 0; it < 2; it++) {
      int idx = t + it * 256;
      int n = idx >> 2;
      int kg = (idx & 3) * 4;
      float4 bv = *(const float4*)(bw + (size_t)n * HD + k0 + kg);
      Bs[kg+0][n] = bv.x; Bs[kg+1][n] = bv.y;
      Bs[kg+2][n] = bv.z; Bs[kg+3][n] = bv.w;
    }
    __syncthreads();
#pragma unroll
    for (int kk = 0; kk < 16; kk++) {
      float a[4], b[8];
#pragma unroll
      for (int r = 0; r < 4; r++) a[r] = As[kk][ty * 4 + r];
#pragma unroll
      for (int c = 0; c < 8; c++) b[c] = Bs[kk][tx * 8 + c];
#pragma unroll
      for (int r = 0; r < 4; r++)
#pragma unroll
        for (int c = 0; c < 8; c++) acc[r][c] = fmaf(a[r], b[c], acc[r][c]);
    }
    __syncthreads();
  }

  int n0 = tx * 8;
#pragma unroll
  for (int r = 0; r < 4; r++) {
    int lr = ty * 4 + r;
    int gm = m0 + lr;
    float4 v0v = make_float4(0.f,0.f,0.f,0.f), v1v = make_float4(0.f,0.f,0.f,0.f);
    if (gm < M) {
      v0v = *(const float4*)(v + (size_t)gm * HD + n0);
      v1v = *(const float4*)(v + (size_t)gm * HD + n0 + 4);
    }
    Ss[lr][n0 + 0] = acc[r][0] * sigmf(v0v.x);
    Ss[lr][n0 + 1] = acc[r][1] * sigmf(v0v.y);
    Ss[lr][n0 + 2] = acc[r][2] * sigmf(v0v.z);
    Ss[lr][n0 + 3] = acc[r][3] * sigmf(v0v.w);
    Ss[lr][n0 + 4] = acc[r][4] * sigmf(v1v.x);
    Ss[lr][n0 + 5] = acc[r][5] * sigmf(v1v.y);
    Ss[lr][n0 + 6] = acc[r][6] * sigmf(v1v.z);
    Ss[lr][n0 + 7] = acc[r][7] * sigmf(v1v.w);
  }
  __syncthreads();

#pragma unroll
  for (int r = 0; r < 4; r++)
#pragma unroll
    for (int c = 0; c < 8; c++) acc[r][c] = 0.0f;

  for (int k0 = 0; k0 < HD; k0 += 16) {
#pragma unroll
    for (int it = 0; it < 2; it++) {
      int idx = t + it * 256;
      int n = idx >> 2;
      int kg = (idx & 3) * 4;
      float4 bv = *(const float4*)(l2 + (size_t)n * HD + k0 + kg);
      Bs[kg+0][n] = bv.x; Bs[kg+1][n] = bv.y;
      Bs[kg+2][n] = bv.z; Bs[kg+3][n] = bv.w;
    }
    __syncthreads();
#pragma unroll
    for (int kk = 0; kk < 16; kk++) {
      float a[4], b[8];
#pragma unroll
      for (int r = 0; r < 4; r++) a[r] = Ss[ty * 4 + r][k0 + kk];
#pragma unroll
      for (int c = 0; c < 8; c++) b[c] = Bs[kk][tx * 8 + c];
#pragma unroll
      for (int r = 0; r < 4; r++)
#pragma unroll
        for (int c = 0; c < 8; c++) acc[r][c] = fmaf(a[r], b[c], acc[r][c]);
    }
    __syncthreads();
  }

#pragma unroll
  for (int r = 0; r < 4; r++) {
    int gm = m0 + ty * 4 + r;
    if (gm >= M) continue;
    uint4 pk;
    pk.x = bfpack(acc[r][0], acc[r][1]);
    pk.y = bfpack(acc[r][2], acc[r][3]);
    pk.z = bfpack(acc[r][4], acc[r][5]);
    pk.w = bfpack(acc[r][6], acc[r][7]);
    *(uint4*)(dagg + (size_t)gm * 64 + tx * 4) = pk;
  }
}

// ------------------------------------------------------------------
// forward gather: agg[a] = sum_in hx[src] * P(d); bf16 table + hx
// contiguous half-split + unroll-2 for memory-level parallelism
// ------------------------------------------------------------------
__global__ __launch_bounds__(256) void gath_fwd_k(
    const int* __restrict__ cptr, const int* __restrict__ cother,
    const float* __restrict__ cdist, const unsigned* __restrict__ T,
    const unsigned* __restrict__ hx, float* __restrict__ agg,
    float inv_h, float hstep)
{
  int a = blockIdx.x * 4 + (threadIdx.x >> 6);
  if (a >= N_ATOMS) return;
  int half = (threadIdx.x >> 5) & 1;
  int l32 = threadIdx.x & 31;
  int ch = l32 * 4;
  int beg = cptr[a], end = cptr[a + 1];
  int cnt = end - beg;
  int h0n = (cnt + 1) >> 1;
  int j    = beg + (half ? h0n : 0);
  int jend = half ? end : (beg + h0n);
  float s0 = 0.f, s1 = 0.f, s2 = 0.f, s3 = 0.f;

  for (; j + 1 < jend; j += 2) {
    int oA = cother[j], oB = cother[j + 1];
    float dA = cdist[j], dB = cdist[j + 1];
    float fiA = dA * inv_h; int iA = (int)fiA; float tA = fiA - (float)iA;
    float fiB = dB * inv_h; int iB = (int)fiB; float tB = fiB - (float)iB;
    float tA2 = tA*tA, tA3 = tA2*tA, tB2 = tB*tB, tB3 = tB2*tB;
    float aA00 = 2.f*tA3 - 3.f*tA2 + 1.f, aA10 = (tA3 - 2.f*tA2 + tA) * hstep;
    float aA01 = 3.f*tA2 - 2.f*tA3,       aA11 = (tA3 - tA2) * hstep;
    float aB00 = 2.f*tB3 - 3.f*tB2 + 1.f, aB10 = (tB3 - 2.f*tB2 + tB) * hstep;
    float aB01 = 3.f*tB2 - 2.f*tB3,       aB11 = (tB3 - tB2) * hstep;
    const unsigned* tpA = T + (size_t)iA * HD + ch;
    const unsigned* tpB = T + (size_t)iB * HD + ch;
    uint4 qa0 = *(const uint4*)(tpA);
    uint4 qa1 = *(const uint4*)(tpA + HD);
    uint4 qb0 = *(const uint4*)(tpB);
    uint4 qb1 = *(const uint4*)(tpB + HD);
    uint2 ha = *(const uint2*)(hx + (size_t)oA * 64 + l32 * 2);
    uint2 hb = *(const uint2*)(hx + (size_t)oB * 64 + l32 * 2);
    float vA0 = aA00*bflo(qa0.x) + aA10*bfhi(qa0.x) + aA01*bflo(qa1.x) + aA11*bfhi(qa1.x);
    float vA1 = aA00*bflo(qa0.y) + aA10*bfhi(qa0.y) + aA01*bflo(qa1.y) + aA11*bfhi(qa1.y);
    float vA2 = aA00*bflo(qa0.z) + aA10*bfhi(qa0.z) + aA01*bflo(qa1.z) + aA11*bfhi(qa1.z);
    float vA3 = aA00*bflo(qa0.w) + aA10*bfhi(qa0.w) + aA01*bflo(qa1.w) + aA11*bfhi(qa1.w);
    float vB0 = aB00*bflo(qb0.x) + aB10*bfhi(qb0.x) + aB01*bflo(qb1.x) + aB11*bfhi(qb1.x);
    float vB1 = aB00*bflo(qb0.y) + aB10*bfhi(qb0.y) + aB01*bflo(qb1.y) + aB11*bfhi(qb1.y);
    float vB2 = aB00*bflo(qb0.z) + aB10*bfhi(qb0.z) + aB01*bflo(qb1.z) + aB11*bfhi(qb1.z);
    float vB3 = aB00*bflo(qb0.w) + aB10*bfhi(qb0.w) + aB01*bflo(qb1.w) + aB11*bfhi(qb1.w);
    s0 = fmaf(bflo(ha.x), vA0, s0); s0 = fmaf(bflo(hb.x), vB0, s0);
    s1 = fmaf(bfhi(ha.x), vA1, s1); s1 = fmaf(bfhi(hb.x), vB1, s1);
    s2 = fmaf(bflo(ha.y), vA2, s2); s2 = fmaf(bflo(hb.y), vB2, s2);
    s3 = fmaf(bfhi(ha.y), vA3, s3); s3 = fmaf(bfhi(hb.y), vB3, s3);
  }
  if (j < jend) {
    int other = cother[j];
    float d = cdist[j];
    float fi = d * inv_h;
    int i0 = (int)fi;
    float t = fi - (float)i0;
    float t2 = t * t, t3 = t2 * t;
    float a00 = 2.f*t3 - 3.f*t2 + 1.f;
    float a10 = (t3 - 2.f*t2 + t) * hstep;
    float a01 = 3.f*t2 - 2.f*t3;
    float a11 = (t3 - t2) * hstep;
    const unsigned* tp = T + (size_t)i0 * HD + ch;
    uint4 q0 = *(const uint4*)(tp);
    uint4 q1 = *(const uint4*)(tp + HD);
    uint2 hp = *(const uint2*)(hx + (size_t)other * 64 + l32 * 2);
    float v0 = a00*bflo(q0.x) + a10*bfhi(q0.x) + a01*bflo(q1.x) + a11*bfhi(q1.x);
    float v1 = a00*bflo(q0.y) + a10*bfhi(q0.y) + a01*bflo(q1.y) + a11*bfhi(q1.y);
    float v2 = a00*bflo(q0.z) + a10*bfhi(q0.z) + a01*bflo(q1.z) + a11*bfhi(q1.z);
    float v3 = a00*bflo(q0.w) + a10*bfhi(q0.w) + a01*bflo(q1.w) + a11*bfhi(q1.w);
    s0 = fmaf(bflo(hp.x), v0, s0);
    s1 = fmaf(bfhi(hp.x), v1, s1);
    s2 = fmaf(bflo(hp.y), v2, s2);
    s3 = fmaf(bfhi(hp.y), v3, s3);
  }
  s0 += __shfl_xor(s0, 32, 64);
  s1 += __shfl_xor(s1, 32, 64);
  s2 += __shfl_xor(s2, 32, 64);
  s3 += __shfl_xor(s3, 32, 64);
  if (half == 0)
    *(float4*)(agg + (size_t)a * HD + ch) = make_float4(s0, s1, s2, s3);
}

// ------------------------------------------------------------------
// backward gather: dhx[a] = sum_out dagg[dst]*P;
// ddslot[j] += <dagg,hx[a]*P'> (slot-indexed, unroll-2)
// ------------------------------------------------------------------
__global__ __launch_bounds__(256) void gath_bwd_k(
    const int* __restrict__ rptr, const int* __restrict__ rother,
    const float* __restrict__ rdist, const unsigned* __restrict__ T,
    const unsigned* __restrict__ dagg, const unsigned* __restrict__ hx,
    float* __restrict__ dhx, float* __restrict__ ddslot,
    float inv_h, float hstep)
{
  int a = blockIdx.x * 4 + (threadIdx.x >> 6);
  if (a >= N_ATOMS) return;
  int half = (threadIdx.x >> 5) & 1;
  int l32 = threadIdx.x & 31;
  int ch = l32 * 4;
  int beg = rptr[a], end = rptr[a + 1];
  int cnt = end - beg;
  int h0n = (cnt + 1) >> 1;
  int j    = beg + (half ? h0n : 0);
  int jend = half ? end : (beg + h0n);
  uint2 hp = *(const uint2*)(hx + (size_t)a * 64 + l32 * 2);
  float h0 = bflo(hp.x), h1 = bfhi(hp.x), h2 = bflo(hp.y), h3 = bfhi(hp.y);
  float s0 = 0.f, s1 = 0.f, s2 = 0.f, s3 = 0.f;

  for (; j + 1 < jend; j += 2) {
    int oA = rother[j], oB = rother[j + 1];
    float dA = rdist[j], dB = rdist[j + 1];
    float fiA = dA * inv_h; int iA = (int)fiA; float tA = fiA - (float)iA;
    float fiB = dB * inv_h; int iB = (int)fiB; float tB = fiB - (float)iB;
    float tA2 = tA*tA, tA3 = tA2*tA, tB2 = tB*tB, tB3 = tB2*tB;
    float aA00 = 2.f*tA3 - 3.f*tA2 + 1.f, aA10 = (tA3 - 2.f*tA2 + tA) * hstep;
    float aA01 = 3.f*tA2 - 2.f*tA3,       aA11 = (tA3 - tA2) * hstep;
    float bA00 = (6.f*tA2 - 6.f*tA) * inv_h, bA10 = 3.f*tA2 - 4.f*tA + 1.f;
    float bA01 = -bA00,                      bA11 = 3.f*tA2 - 2.f*tA;
    float aB00 = 2.f*tB3 - 3.f*tB2 + 1.f, aB10 = (tB3 - 2.f*tB2 + tB) * hstep;
    float aB01 = 3.f*tB2 - 2.f*tB3,       aB11 = (tB3 - tB2) * hstep;
    float bB00 = (6.f*tB2 - 6.f*tB) * inv_h, bB10 = 3.f*tB2 - 4.f*tB + 1.f;
    float bB01 = -bB00,                      bB11 = 3.f*tB2 - 2.f*tB;
    const unsigned* tpA = T + (size_t)iA * HD + ch;
    const unsigned* tpB = T + (size_t)iB * HD + ch;
    uint4 qa0 = *(const uint4*)(tpA);
    uint4 qa1 = *(const uint4*)(tpA + HD);
    uint4 qb0 = *(const uint4*)(tpB);
    uint4 qb1 = *(const uint4*)(tpB + HD);
    uint2 da = *(const uint2*)(dagg + (size_t)oA * 64 + l32 * 2);
    uint2 db = *(const uint2*)(dagg + (size_t)oB * 64 + l32 * 2);
    float dA0 = bflo(da.x), dA1 = bfhi(da.x), dA2 = bflo(da.y), dA3 = bfhi(da.y);
    float dB0 = bflo(db.x), dB1 = bfhi(db.x), dB2 = bflo(db.y), dB3 = bfhi(db.y);
    float vA0 = aA00*bflo(qa0.x) + aA10*bfhi(qa0.x) + aA01*bflo(qa1.x) + aA11*bfhi(qa1.x);
    float vA1 = aA00*bflo(qa0.y) + aA10*bfhi(qa0.y) + aA01*bflo(qa1.y) + aA11*bfhi(qa1.y);
    float vA2 = aA00*bflo(qa0.z) + aA10*bfhi(qa0.z) + aA01*bflo(qa1.z) + aA11*bfhi(qa1.z);
    float vA3 = aA00*bflo(qa0.w) + aA10*bfhi(qa0.w) + aA01*bflo(qa1.w) + aA11*bfhi(qa1.w);
    float gA0 = bA00*bflo(qa0.x) + bA10*bfhi(qa0.x) + bA01*bflo(qa1.x) + bA11*bfhi(qa1.x);
    float gA1 = bA00*bflo(qa0.y) + bA10*bfhi(qa0.y) + bA01*bflo(qa1.y) + bA11*bfhi(qa1.y);
    float gA2 = bA00*bflo(qa0.z) + bA10*bfhi(qa0.z) + bA01*bflo(qa1.z) + bA11*bfhi(qa1.z);
    float gA3 = bA00*bflo(qa0.w) + bA10*bfhi(qa0.w) + bA01*bflo(qa1.w) + bA11*bfhi(qa1.w);
    float vB0 = aB00*bflo(qb0.x) + aB10*bfhi(qb0.x) + aB01*bflo(qb1.x) + aB11*bfhi(qb1.x);
    float vB1 = aB00*bflo(qb0.y) + aB10*bfhi(qb0.y) + aB01*bflo(qb1.y) + aB11*bfhi(qb1.y);
    float vB2 = aB00*bflo(qb0.z) + aB10*bfhi(qb0.z) + aB01*bflo(qb1.z) + aB11*bfhi(qb1.z);
    float vB3 = aB00*bflo(qb0.w) + aB10*bfhi(qb0.w) + aB01*bflo(qb1.w) + aB11*bfhi(qb1.w);
    float gB0 = bB00*bflo(qb0.x) + bB10*bfhi(qb0.x) + bB01*bflo(qb1.x) + bB11*bfhi(qb1.x);
    float gB1 = bB00*bflo(qb0.y) + bB10*bfhi(qb0.y) + bB01*bflo(qb1.y) + bB11*bfhi(qb1.y);
    float gB2 = bB00*bflo(qb0.z) + bB10*bfhi(qb0.z) + bB01*bflo(qb1.z) + bB11*bfhi(qb1.z);
    float gB3 = bB00*bflo(qb0.w) + bB10*bfhi(qb0.w) + bB01*bflo(qb1.w) + bB11*bfhi(qb1.w);
    s0 = fmaf(dA0, vA0, s0); s0 = fmaf(dB0, vB0, s0);
    s1 = fmaf(dA1, vA1, s1); s1 = fmaf(dB1, vB1, s1);
    s2 = fmaf(dA2, vA2, s2); s2 = fmaf(dB2, vB2, s2);
    s3 = fmaf(dA3, vA3, s3); s3 = fmaf(dB3, vB3, s3);
    float dotA = dA0*h0*gA0 + dA1*h1*gA1 + dA2*h2*gA2 + dA3*h3*gA3;
    float dotB = dB0*h0*gB0 + dB1*h1*gB1 + dB2*h2*gB2 + dB3*h3*gB3;
#pragma unroll
    for (int off = 16; off > 0; off >>= 1) {
      dotA += __shfl_down(dotA, off, 32);
      dotB += __shfl_down(dotB, off, 32);
    }
    if (l32 == 0) {
      ddslot[j]     += dotA;
      ddslot[j + 1] += dotB;
    }
  }
  if (j < jend) {
    int other = rother[j];
    float d = rdist[j];
    float fi = d * inv_h;
    int i0 = (int)fi;
    float t = fi - (float)i0;
    float t2 = t * t, t3 = t2 * t;
    float a00 = 2.f*t3 - 3.f*t2 + 1.f;
    float a10 = (t3 - 2.f*t2 + t) * hstep;
    float a01 = 3.f*t2 - 2.f*t3;
    float a11 = (t3 - t2) * hstep;
    float b00 = (6.f*t2 - 6.f*t) * inv_h;
    float b10 = 3.f*t2 - 4.f*t + 1.f;
    float b01 = -b00;
    float b11 = 3.f*t2 - 2.f*t;
    const unsigned* tp = T + (size_t)i0 * HD + ch;
    uint4 q0 = *(const uint4*)(tp);
    uint4 q1 = *(const uint4*)(tp + HD);
    uint2 dp = *(const uint2*)(dagg + (size_t)other * 64 + l32 * 2);
    float da0 = bflo(dp.x), da1 = bfhi(dp.x), da2 = bflo(dp.y), da3 = bfhi(dp.y);
    float v0 = a00*bflo(q0.x) + a10*bfhi(q0.x) + a01*bflo(q1.x) + a11*bfhi(q1.x);
    float v1 = a00*bflo(q0.y) + a10*bfhi(q0.y) + a01*bflo(q1.y) + a11*bfhi(q1.y);
    float v2 = a00*bflo(q0.z) + a10*bfhi(q0.z) + a01*bflo(q1.z) + a11*bfhi(q1.z);
    float v3 = a00*bflo(q0.w) + a10*bfhi(q0.w) + a01*bflo(q1.w) + a11*bfhi(q1.w);
    float g0 = b00*bflo(q0.x) + b10*bfhi(q0.x) + b01*bflo(q1.x) + b11*bfhi(q1.x);
    float g1 = b00*bflo(q0.y) + b10*bfhi(q0.y) + b01*bflo(q1.y) + b11*bfhi(q1.y);
    float g2 = b00*bflo(q0.z) + b10*bfhi(q0.z) + b01*bflo(q1.z) + b11*bfhi(q1.z);
    float g3 = b00*bflo(q0.w) + b10*bfhi(q0.w) + b01*bflo(q1.w) + b11*bfhi(q1.w);
    s0 = fmaf(da0, v0, s0);
    s1 = fmaf(da1, v1, s1);
    s2 = fmaf(da2, v2, s2);
    s3 = fmaf(da3, v3, s3);
    float dot = da0*h0*g0 + da1*h1*g1 + da2*h2*g2 + da3*h3*g3;
#pragma unroll
    for (int off = 16; off > 0; off >>= 1) dot += __shfl_down(dot, off, 32);
    if (l32 == 0) ddslot[j] += dot;
  }
  s0 += __shfl_xor(s0, 32, 64);
  s1 += __shfl_xor(s1, 32, 64);
  s2 += __shfl_xor(s2, 32, 64);
  s3 += __shfl_xor(s3, 32, 64);
  if (half == 0)
    *(float4*)(dhx + (size_t)a * HD + ch) = make_float4(s0, s1, s2, s3);
}

// ------------------------------------------------------------------
// fused head: s = h4@hw1 + hb1; ea[a] = ssp(s)@hw2 + hb2 (plain store);
// gh = (sigm(s)*hw2) @ hw1^T    (Ss padded to 69)
// ------------------------------------------------------------------
__global__ __launch_bounds__(256) void headf_k(
    const float* __restrict__ h4, const float* __restrict__ hw1,
    const float* __restrict__ hb1, const float* __restrict__ hw2,
    const float* __restrict__ hb2, float* __restrict__ ea,
    float* __restrict__ gh)
{
  __shared__ float As[16][68];
  __shared__ float Bs[16][132];
  __shared__ float Ss[64][69];
  __shared__ float red[64][17];
  int t = threadIdx.x;
  int tx = t & 15, ty = t >> 4;
  int m0 = blockIdx.x * 64;

  float acc4[4][4];
#pragma unroll
  for (int r = 0; r < 4; r++)
#pragma unroll
    for (int c = 0; c < 4; c++) acc4[r][c] = 0.0f;

  for (int k0 = 0; k0 < HD; k0 += 16) {
    {
      int rrow = t >> 2;
      int kg = (t & 3) * 4;
      int gm = m0 + rrow;
      float4 av = make_float4(0.f, 0.f, 0.f, 0.f);
      if (gm < N_ATOMS) av = *(const float4*)(h4 + (size_t)gm * HD + k0 + kg);
      As[kg+0][rrow] = av.x; As[kg+1][rrow] = av.y;
      As[kg+2][rrow] = av.z; As[kg+3][rrow] = av.w;
    }
    if (t < 256) {
      int kk = t >> 4;
      int n4 = (t & 15) * 4;
      float4 bv = *(const float4*)(hw1 + (size_t)(k0 + kk) * 64 + n4);
      *(float4*)&Bs[kk][n4] = bv;
    }
    __syncthreads();
#pragma unroll
    for (int kk = 0; kk < 16; kk++) {
      float a[4], b[4];
#pragma unroll
      for (int r = 0; r < 4; r++) a[r] = As[kk][ty * 4 + r];
#pragma unroll
      for (int c = 0; c < 4; c++) b[c] = Bs[kk][tx * 4 + c];
#pragma unroll
      for (int r = 0; r < 4; r++)
#pragma unroll
        for (int c = 0; c < 4; c++) acc4[r][c] = fmaf(a[r], b[c], acc4[r][c]);
    }
    __syncthreads();
  }

  {
    int n0 = tx * 4;
    float b1v[4], w2v[4];
#pragma unroll
    for (int c = 0; c < 4; c++) { b1v[c] = hb1[n0 + c]; w2v[c] = hw2[n0 + c]; }
#pragma unroll
    for (int r = 0; r < 4; r++) {
      int lr = ty * 4 + r;
      float p = 0.0f;
#pragma unroll
      for (int c = 0; c < 4; c++) {
        float x = acc4[r][c] + b1v[c];
        p += sspf(x) * w2v[c];
        Ss[lr][n0 + c] = sigmf(x) * w2v[c];
      }
      red[lr][tx] = p;
    }
  }
  __syncthreads();
  if (t < 64) {
    int gm = m0 + t;
    if (gm < N_ATOMS) {
      float s = hb2[0];
#pragma unroll
      for (int j = 0; j < 16; j++) s += red[t][j];
      ea[gm] = s;
    }
  }

  float acc[4][8];
#pragma unroll
  for (int r = 0; r < 4; r++)
#pragma unroll
    for (int c = 0; c < 8; c++) acc[r][c] = 0.0f;

  for (int j0 = 0; j0 < 64; j0 += 16) {
#pragma unroll
    for (int it = 0; it < 2; it++) {
      int idx = t + it * 256;
      int n = idx >> 2;
      int jg = (idx & 3) * 4;
      float4 bv = *(const float4*)(hw1 + (size_t)n * 64 + j0 + jg);
      Bs[jg+0][n] = bv.x; Bs[jg+1][n] = bv.y;
      Bs[jg+2][n] = bv.z; Bs[jg+3][n] = bv.w;
    }
    __syncthreads();
#pragma unroll
    for (int kk = 0; kk < 16; kk++) {
      float a[4], b[8];
#pragma unroll
      for (int r = 0; r < 4; r++) a[r] = Ss[ty * 4 + r][j0 + kk];
#pragma unroll
      for (int c = 0; c < 8; c++) b[c] = Bs[kk][tx * 8 + c];
#pragma unroll
      for (int r = 0; r < 4; r++)
#pragma unroll
        for (int c = 0; c < 8; c++) acc[r][c] = fmaf(a[r], b[c], acc[r][c]);
    }
    __syncthreads();
  }

  int n0 = tx * 8;
#pragma unroll
  for (int r = 0; r < 4; r++) {
    int gm = m0 + ty * 4 + r;
    if (gm >= N_ATOMS) continue;
    *(float4*)(gh + (size_t)gm * HD + n0)     = *(float4*)&acc[r][0];
    *(float4*)(gh + (size_t)gm * HD + n0 + 4) = *(float4*)&acc[r][4];
  }
}

// ------------------------------------------------------------------
// per-molecule energy reduction (batch is sorted; binary search bounds)
// ------------------------------------------------------------------
__global__ __launch_bounds__(64) void ered_k(
    const int* __restrict__ batch, const float* __restrict__ ea,
    float* __restrict__ energy)
{
  int m = blockIdx.x;
  int lo = 0, hi = N_ATOMS;
  while (lo < hi) { int mid = (lo + hi) >> 1; if (batch[mid] < m) lo = mid + 1; else hi = mid; }
  int beg = lo;
  lo = beg; hi = N_ATOMS;
  while (lo < hi) { int mid = (lo + hi) >> 1; if (batch[mid] < m + 1) lo = mid + 1; else hi = mid; }
  int end = lo;
  float s = 0.0f;
  for (int i = beg + threadIdx.x; i < end; i += 64) s += ea[i];
#pragma unroll
  for (int off = 32; off > 0; off >>= 1) s += __shfl_down(s, off, 64);
  if (threadIdx.x == 0) energy[m] = s;
}

// ------------------------------------------------------------------
// force gather: 8 lanes per atom, both CSR directions, no atomics
// ------------------------------------------------------------------
__global__ __launch_bounds__(256) void forceg_k(
    const int* __restrict__ rptr, const int* __restrict__ rother,
    const float* __restrict__ rdist,
    const int* __restrict__ cptr, const int* __restrict__ cother,
    const float* __restrict__ cdist, const int* __restrict__ cslot,
    const float* __restrict__ ddslot, const float* __restrict__ pos,
    float* __restrict__ force)
{
  int idx = blockIdx.x * 256 + threadIdx.x;
  int a = idx >> 3;
  int g = idx & 7;
  if (a >= N_ATOMS) return;
  float px = pos[3*a+0], py = pos[3*a+1], pz = pos[3*a+2];
  float fx = 0.f, fy = 0.f, fz = 0.f;
  int beg = rptr[a], end = rptr[a+1];
  for (int j = beg + g; j < end; j += 8) {
    int o = rother[j];
    float w = ddslot[j] / rdist[j];
    fx -= w * (px - pos[3*o+0]);
    fy -= w * (py - pos[3*o+1]);
    fz -= w * (pz - pos[3*o+2]);
  }
  beg = cptr[a]; end = cptr[a+1];
  for (int j = beg + g; j < end; j += 8) {
    int o = cother[j];
    float w = ddslot[cslot[j]] / cdist[j];
    fx -= w * (px - pos[3*o+0]);
    fy -= w * (py - pos[3*o+1]);
    fz -= w * (pz - pos[3*o+2]);
  }
#pragma unroll
  for (int off = 4; off > 0; off >>= 1) {
    fx += __shfl_down(fx, off, 8);
    fy += __shfl_down(fy, off, 8);
    fz += __shfl_down(fz, off, 8);
  }
  if (g == 0) {
    force[3*a+0] = fx;
    force[3*a+1] = fy;
    force[3*a+2] = fz;
  }
}

// ------------------------------------------------------------------
// host launch
// ------------------------------------------------------------------
static inline int nblk(int m) { return (m + 63) / 64; }

extern "C" void kernel_launch(void* const* d_in, const int* in_sizes, int n_in,
                              void* d_out, int out_size, void* d_ws, size_t ws_size,
                              hipStream_t stream)
{
  const float* pos   = (const float*)d_in[0];
  const int*   z     = (const int*)d_in[1];
  const int*   batch = (const int*)d_in[2];
  const int*   eidx  = (const int*)d_in[3];
  const float* emb   = (const float*)d_in[4];
  const float* mlp_w1 = (const float*)d_in[5];
  const float* mlp_b1 = (const float*)d_in[6];
  const float* mlp_w2 = (const float*)d_in[7];
  const float* mlp_b2 = (const float*)d_in[8];
  const float* lin1_w = (const float*)d_in[9];
  const float* lin2_w = (const float*)d_in[10];
  const float* lin2_b = (const float*)d_in[11];
  const float* blk_w  = (const float*)d_in[12];
  const float* blk_b  = (const float*)d_in[13];
  const float* hw1 = (const float*)d_in[14];
  const float* hb1 = (const float*)d_in[15];
  const float* hw2 = (const float*)d_in[16];
  const float* hb2 = (const float*)d_in[17];

  float* out = (float*)d_out;          // [NMOL] energies ++ [N,3] forces
  float* ws  = (float*)d_ws;

  const int* row = eidx;
  const int* col = eidx + N_EDGES;

  const size_t NH = (size_t)N_ATOMS * HD;
  size_t o = 0;
  float* dist   = ws + o; o += N_EDGES;
  float* ddslot = ws + o; o += N_EDGES;
  int* cptr   = (int*)(ws + o); o += N_ATOMS + 1;
  int* rptr   = (int*)(ws + o); o += N_ATOMS + 1;
  int* cother = (int*)(ws + o); o += N_EDGES;
  int* rother = (int*)(ws + o); o += N_EDGES;
  int* slotof = (int*)(ws + o); o += N_EDGES;
  int* cslot  = (int*)(ws + o); o += N_EDGES;
  float* cdist = ws + o; o += N_EDGES;
  float* rdist = ws + o; o += N_EDGES;
  int* cur0   = (int*)(ws + o); o += N_ATOMS;
  int* cur1   = (int*)(ws + o); o += N_ATOMS;
  float* hxb[4];   // stored as bf16 pairs (uint, 64/row)
  for (int i = 0; i < 4; i++) { hxb[i] = ws + o; o += NH; }
  float* vbuf[4];
  for (int i = 0; i < 4; i++) { vbuf[i] = ws + o; o += NH; }
  float* hA  = ws + o; o += NH;
  float* hB  = ws + o; o += NH;
  float* agg = ws + o; o += NH;       // fwd agg / bwd dhx / table temps
  float* g0b = ws + o; o += NH;
  float* g1b = ws + o; o += NH;
  float* dgb = ws + o; o += NH;       // dagg(bf16) / ea / table temps

  // table: bf16 pairs, 1 uint per (node,ch)
  int NT = 1024;
  while (NT > 128) {
    size_t need = o + (size_t)NLAY * (NT + 1) * HD;
    if (need * sizeof(float) <= ws_size) break;
    NT >>= 1;
  }
  const int NN = NT + 1;
  const float hstep = FCUT / (float)NT;
  const float inv_h = (float)NT / FCUT;
  unsigned* T = (unsigned*)(ws + o); o += (size_t)NLAY * NN * HD;

  hipMemsetAsync(ddslot, 0, N_EDGES * sizeof(float), stream);

  geom_k<<<(N_EDGES + 255) / 256, 256, 0, stream>>>(pos, row, col, dist);

  // ---------------- CSR build (both directions) ----------------
  {
    const int EB = (N_EDGES + 255) / 256;
    hipMemsetAsync(cur0, 0, N_ATOMS * sizeof(int), stream);
    hipMemsetAsync(cur1, 0, N_ATOMS * sizeof(int), stream);
    hist_k<<<EB, 256, 0, stream>>>(col, cur0);
    hist_k<<<EB, 256, 0, stream>>>(row, cur1);
    scan_k<<<1, 256, 0, stream>>>(cur0, cptr);
    scan_k<<<1, 256, 0, stream>>>(cur1, rptr);
    hipMemcpyAsync(cur0, cptr, N_ATOMS * sizeof(int), hipMemcpyDeviceToDevice, stream);
    hipMemcpyAsync(cur1, rptr, N_ATOMS * sizeof(int), hipMemcpyDeviceToDevice, stream);
    scat_row_k<<<EB, 256, 0, stream>>>(row, col, dist, cur1, rother, rdist, slotof);
    scat_col_k<<<EB, 256, 0, stream>>>(row, col, dist, cur0, cother, cdist, slotof, cslot);
  }

  // ---------------- build filter tables (all 4 layers) ----------------
  {
    const size_t LNH = (size_t)NN * HD;
    float* Anode  = agg;
    float* dAnode = agg + LNH;
    float* t1 = dgb;
    float* u  = g0b;
    float* s  = g1b;
    float* sp = hA;
    nodeA_k<<<((int)LNH + 255) / 256, 256, 0, stream>>>(Anode, dAnode, NN, hstep);
    dim3 gB(nblk(NN), NLAY);
    gemm128b_k<<<gB, 256, 0, stream>>>(Anode, 0, mlp_w1, (size_t)HD*HD,
                                       mlp_b1, HD, t1, LNH, NN);
    gemm128b_k<<<gB, 256, 0, stream>>>(dAnode, 0, mlp_w1, (size_t)HD*HD,
                                       nullptr, 0, u, LNH, NN);
    int tot = (int)(NLAY * LNH);
    nodeact_k<<<(tot + 255) / 256, 256, 0, stream>>>(t1, u, s, sp, tot);
    float* P0 = dgb;
    float* D0 = g0b;
    gemm128b_k<<<gB, 256, 0, stream>>>(s, LNH, mlp_w2, (size_t)HD*HD,
                                       mlp_b2, HD, P0, LNH, NN);
    gemm128b_k<<<gB, 256, 0, stream>>>(sp, LNH, mlp_w2, (size_t)HD*HD,
                                       nullptr, 0, D0, LNH, NN);
    nodecomb_k<<<(tot + 255) / 256, 256, 0, stream>>>(P0, D0, T, NN, hstep);
  }

  h0_k<<<(N_ATOMS * HD + 255) / 256, 256, 0, stream>>>(emb, z, hA);

  const int AB = (N_ATOMS + 3) / 4;
  const int GB = nblk(N_ATOMS);

  // hx for layer 0 (later layers fused into ftail phase 3)
  gemm128_k<0,false,true><<<GB, 256, 0, stream>>>(hA, lin1_w, nullptr, nullptr, hxb[0], N_ATOMS);

  // ---------------- forward ----------------
  float* hcur = hA;
  float* hnxt = hB;
  for (int i = 0; i < NLAY; i++) {
    const float* l2 = lin2_w + (size_t)i * HD * HD;
    const float* l2b = lin2_b + (size_t)i * HD;
    const float* bw = blk_w + (size_t)i * HD * HD;
    const float* bb = blk_b + (size_t)i * HD;
    const unsigned* Tl = T + (size_t)i * NN * HD;
    const float* l1n = (i + 1 < NLAY) ? lin1_w + (size_t)(i + 1) * HD * HD : nullptr;
    unsigned* hxn = (i + 1 < NLAY) ? (unsigned*)hxb[i + 1] : nullptr;

    gath_fwd_k<<<AB, 256, 0, stream>>>(cptr, cother, cdist, Tl, (const unsigned*)hxb[i], agg, inv_h, hstep);
    ftail_k<<<GB, 256, 0, stream>>>(agg, l2, l2b, bw, bb, hcur, l1n, vbuf[i], hnxt, hxn, N_ATOMS);
    float* tmp = hcur; hcur = hnxt; hnxt = tmp;
  }

  // ---------------- head (fused) + per-molecule energy ----------------
  float* ea = dgb;   // per-atom energy scratch; dgb free here
  headf_k<<<GB, 256, 0, stream>>>(hcur, hw1, hb1, hw2, hb2, ea, g0b);
  ered_k<<<NMOL, 64, 0, stream>>>(batch, ea, out);

  // ---------------- backward ----------------
  float* gcur = g0b;
  float* gnxt = g1b;
  for (int i = NLAY - 1; i >= 0; i--) {
    const float* l1 = lin1_w + (size_t)i * HD * HD;
    const float* l2 = lin2_w + (size_t)i * HD * HD;
    const float* bw = blk_w + (size_t)i * HD * HD;
    const unsigned* Tl = T + (size_t)i * NN * HD;

    bhead_k<<<GB, 256, 0, stream>>>(gcur, bw, vbuf[i], l2, (unsigned*)dgb, N_ATOMS);
    gath_bwd_k<<<AB, 256, 0, stream>>>(rptr, rother, rdist, Tl, (const unsigned*)dgb,
                                       (const unsigned*)hxb[i], agg, ddslot, inv_h, hstep);
    if (i > 0) {
      gemm128_k<1,true,false><<<GB, 256, 0, stream>>>(agg, l1, nullptr, gcur, gnxt, N_ATOMS);
      float* tmp = gcur; gcur = gnxt; gnxt = tmp;
    }
  }

  forceg_k<<<(N_ATOMS * 8 + 255) / 256, 256, 0, stream>>>(
      rptr, rother, rdist, cptr, cother, cdist, cslot, ddslot, pos, out + NMOL);
}